// Round 5
// baseline (2800.802 us; speedup 1.0000x reference)
//
#include <hip/hip_runtime.h>
#include <hip/hip_bf16.h>

// DecoderRNN: B=32,P=196,E=H=A=512,V=32000,T=50
// v6: persistent scan, latency+residency version.
//  - Wcat2 normally cached (round-4 NT flag made it stream 12 MB/step from HBM).
//  - L2 residency budget per XCD (<4MB): Wcat2 slice 1.5 MB + encatt as bf16
//    (0.8 MB) + feat via F2-hi bf16 (0.8 MB).
//  - finalize de-replicated: p1a finalizes a 64-elem h-slice per block (gpart
//    coherent reads 16->2 MB/step), h broadcast via tiny coherent hbuf; p1b does
//    dec_att/scores.  4 barriers/step.
//  - p3 batch-stages all 12 k-steps then runs 24 MFMAs back-to-back (was 12
//    serial sync+latency rounds).  Plain coherent stores to gpart (no atomics).

typedef __attribute__((ext_vector_type(8))) short short8;
typedef __attribute__((ext_vector_type(4))) float f32x4;
typedef unsigned long long u64;

#define BARSTRIDE 32  // uints between counters (128 B)
#define NBAR 224      // sync points used: 200

__device__ __forceinline__ unsigned short f2bf(float x) {
  __hip_bfloat16 h = __float2bfloat16(x);
  return __builtin_bit_cast(unsigned short, h);
}
__device__ __forceinline__ float bf2f(unsigned short u) {
  unsigned int v = ((unsigned int)u) << 16;
  return __builtin_bit_cast(float, v);
}
__device__ __forceinline__ void gl_lds16(const void* g, void* l) {
  __builtin_amdgcn_global_load_lds(
      (const __attribute__((address_space(1))) unsigned int*)g,
      (__attribute__((address_space(3))) unsigned int*)l, 16, 0, 0);
}
// coherent (agent-scope, cache-bypassing, NO cache-maintenance) accessors
__device__ __forceinline__ u64 cload64(const void* p) {
  return __hip_atomic_load((const u64*)p, __ATOMIC_RELAXED, __HIP_MEMORY_SCOPE_AGENT);
}
__device__ __forceinline__ float cloadf(const void* p) {
  unsigned int v = __hip_atomic_load((const unsigned int*)p, __ATOMIC_RELAXED,
                                     __HIP_MEMORY_SCOPE_AGENT);
  return __builtin_bit_cast(float, v);
}
__device__ __forceinline__ float2 bc2(u64 v) { return __builtin_bit_cast(float2, v); }
__device__ __forceinline__ void cstore32(void* p, unsigned int v) {
  __hip_atomic_store((unsigned int*)p, v, __ATOMIC_RELAXED, __HIP_MEMORY_SCOPE_AGENT);
}
__device__ __forceinline__ void cstoref(void* p, float v) {
  cstore32(p, __builtin_bit_cast(unsigned int, v));
}
__device__ __forceinline__ void cstore64(void* p, u64 v) {
  __hip_atomic_store((u64*)p, v, __ATOMIC_RELAXED, __HIP_MEMORY_SCOPE_AGENT);
}

// grid barrier: dedicated counter per sync point; NO cache-wide fences.
__device__ __forceinline__ void gbar(unsigned int* ctr) {
  asm volatile("s_waitcnt vmcnt(0)" ::: "memory");
  __syncthreads();
  if (threadIdx.x == 0) {
    __hip_atomic_fetch_add(ctr, 1u, __ATOMIC_RELAXED, __HIP_MEMORY_SCOPE_AGENT);
    while (__hip_atomic_load(ctr, __ATOMIC_RELAXED, __HIP_MEMORY_SCOPE_AGENT) < 256u)
      __builtin_amdgcn_s_sleep(2);
  }
  asm volatile("" ::: "memory");
  __syncthreads();
}

__global__ void k_zero(unsigned int* __restrict__ p, int n) {
  int i = blockIdx.x * blockDim.x + threadIdx.x;
  if (i < n) p[i] = 0;
}

// ---- prep: f32 [rows,512] -> bf16 split [rows,1024] ([0,512)=hi, [512,1024)=lo)
__global__ void k_split(const float* __restrict__ src, unsigned short* __restrict__ dst,
                        int rows, int src_ld) {
  int n = rows * 512;
  for (int i = blockIdx.x * blockDim.x + threadIdx.x; i < n; i += gridDim.x * blockDim.x) {
    int r = i >> 9, c = i & 511;
    float x = src[(size_t)r * src_ld + c];
    unsigned short hi = f2bf(x);
    unsigned short lo = f2bf(x - bf2f(hi));
    dst[(size_t)r * 1024 + c] = hi;
    dst[(size_t)r * 1024 + 512 + c] = lo;
  }
}

// ---- prep: plain f32 -> bf16
__global__ void k_bf16c(const float* __restrict__ src, unsigned short* __restrict__ dst, int n) {
  for (int i = blockIdx.x * blockDim.x + threadIdx.x; i < n; i += gridDim.x * blockDim.x)
    dst[i] = f2bf(src[i]);
}

// ---- prep: Wcat2 [2048 j][2048]: cols [0,512)=hi(W_ih[j,512+c]) [512,1024)=hi(W_hh[j,c]),
//      [1024,2048) = same but lo.  Matches xh2 layout [awe_hi|h_hi|awe_lo|h_lo].
__global__ void k_wcat2(const float* __restrict__ Wih, const float* __restrict__ Whh,
                        unsigned short* __restrict__ dst) {
  int n = 2048 * 1024;
  for (int i = blockIdx.x * blockDim.x + threadIdx.x; i < n; i += gridDim.x * blockDim.x) {
    int j = i >> 10, c = i & 1023;
    float x = (c < 512) ? Wih[(size_t)j * 1024 + 512 + c] : Whh[(size_t)j * 512 + (c - 512)];
    unsigned short hi = f2bf(x);
    unsigned short lo = f2bf(x - bf2f(hi));
    dst[(size_t)j * 2048 + c] = hi;
    dst[(size_t)j * 2048 + 1024 + c] = lo;
  }
}

// ---- prep: X2 [1600,1024] split-bf16 of emb[captions]; row m = b*50+t
__global__ void k_xgather(const int* __restrict__ captions, const float* __restrict__ emb,
                          unsigned short* __restrict__ X2) {
  int n = 1600 * 512;
  for (int i = blockIdx.x * blockDim.x + threadIdx.x; i < n; i += gridDim.x * blockDim.x) {
    int m = i >> 9, c = i & 511;
    int tok = captions[m];
    float x = emb[(size_t)tok * 512 + c];
    unsigned short hi = f2bf(x);
    unsigned short lo = f2bf(x - bf2f(hi));
    X2[(size_t)m * 1024 + c] = hi;
    X2[(size_t)m * 1024 + 512 + c] = lo;
  }
}

// ---- split-bf16 GEMM: C[m,n] = sum_k A[m,:]·B[n,:] (3-term hi/lo) + bias1[n] + bias2[n]
// A2 [M,1024], B2 [N,1024]. 128x128 tile, m97 pattern.
// Bijective XCD-chunked swizzle, M-fastest decode: same-N-panel tiles co-reside on one XCD.
__global__ void k_gemm(const unsigned short* __restrict__ A2, const unsigned short* __restrict__ B2,
                       float* __restrict__ C, const float* __restrict__ bias1,
                       const float* __restrict__ bias2, int M, int N) {
  __shared__ short As[128 * 32];
  __shared__ short Bs[128 * 32];
  const int tid = threadIdx.x;
  const int lane = tid & 63;
  const int w = tid >> 6, wm = w >> 1, wn = w & 1;

  const int nbx = gridDim.x, nby = gridDim.y;
  const int nwg = nbx * nby;
  const int bidl = blockIdx.y * nbx + blockIdx.x;
  int flat = bidl;
  if (nwg >= 16) {  // bijective chunked XCD swizzle (m204 formula)
    const int q = nwg >> 3, rrem = nwg & 7;
    const int xcd = bidl & 7, idx = bidl >> 3;
    flat = (xcd < rrem) ? xcd * (q + 1) + idx : rrem * (q + 1) + (xcd - rrem) * q + idx;
  }
  const int mb = flat % nby, nb = flat / nby;  // M fastest: same-N tiles contiguous
  const int m0 = mb * 128, n0 = nb * 128;

  f32x4 acc[4][4];
#pragma unroll
  for (int i = 0; i < 4; ++i)
#pragma unroll
    for (int j = 0; j < 4; ++j) acc[i][j] = (f32x4){0.f, 0.f, 0.f, 0.f};

  const int r0 = tid >> 2;
  const int ce = (tid & 3) << 3;
  int am0 = m0 + r0;      if (am0 >= M) am0 = 0;
  int am1 = m0 + 64 + r0; if (am1 >= M) am1 = 0;
  const int bn0 = n0 + r0, bn1 = n0 + 64 + r0;

  for (int ks = 0; ks < 48; ++ks) {
    int t_ = ks >> 4, k = (ks & 15) << 5;
    int acol = (t_ == 2) ? 512 + k : k;
    int bcol = (t_ == 1) ? 512 + k : k;
    __syncthreads();
    gl_lds16(A2 + (size_t)am0 * 1024 + acol + ce, As + tid * 8);
    gl_lds16(A2 + (size_t)am1 * 1024 + acol + ce, As + 2048 + tid * 8);
    gl_lds16(B2 + (size_t)bn0 * 1024 + bcol + ce, Bs + tid * 8);
    gl_lds16(B2 + (size_t)bn1 * 1024 + bcol + ce, Bs + 2048 + tid * 8);
    __syncthreads();
    short8 af[4], bf[4];
#pragma unroll
    for (int mi = 0; mi < 4; ++mi) {
      int row = wm * 64 + mi * 16 + (lane & 15);
      af[mi] = *(const short8*)(As + row * 32 + (lane >> 4) * 8);
    }
#pragma unroll
    for (int ni = 0; ni < 4; ++ni) {
      int row = wn * 64 + ni * 16 + (lane & 15);
      bf[ni] = *(const short8*)(Bs + row * 32 + (lane >> 4) * 8);
    }
#pragma unroll
    for (int mi = 0; mi < 4; ++mi)
#pragma unroll
      for (int ni = 0; ni < 4; ++ni)
        acc[mi][ni] = __builtin_amdgcn_mfma_f32_16x16x32_bf16(af[mi], bf[ni], acc[mi][ni], 0, 0, 0);
  }

  const int mbb = m0 + wm * 64, nbb = n0 + wn * 64;
#pragma unroll
  for (int ni = 0; ni < 4; ++ni) {
    int n = nbb + ni * 16 + (lane & 15);
    float bv = 0.f;
    if (bias1) bv += bias1[n];
    if (bias2) bv += bias2[n];
#pragma unroll
    for (int mi = 0; mi < 4; ++mi)
#pragma unroll
      for (int r = 0; r < 4; ++r) {
        int m = mbb + mi * 16 + (lane >> 4) * 4 + r;
        if (m < M) C[(size_t)m * N + n] = acc[mi][ni][r] + bv;
      }
  }
}

// ---- persistent scan: 50 steps, 4 phases/step, all 256 blocks busy each phase.
// block = (b = bid>>3, sblk = bid&7); XCD = bid%8 = sblk -> slices partition L2.
// p1a: finalize LSTM u-slice [sblk*64,+64) (gpart coherent 8KB/block) -> hbuf/H2/xh2.
// p1b: read full h (hbuf 2KB), dec_att a-slice, partial scores -> spart.
// p2 : combine spart, softmax (replicated), awe e-slice (F2-hi) -> xh2.
// p3 : gates MFMA (batch-staged 12 k-steps, 24 MFMAs), stores -> gpart.
__global__ void __launch_bounds__(256, 1) k_scan(
    const float* __restrict__ gates_x, unsigned short* __restrict__ H2,
    unsigned short* xh2, const unsigned short* __restrict__ Wdec2,
    const float* __restrict__ b_dec, const unsigned short* __restrict__ encbf,
    const float* __restrict__ Wfull, const unsigned short* __restrict__ F2,
    const unsigned short* __restrict__ Wcat2, float* gpart, float* spart,
    float* hbuf, unsigned int* bar) {
  const int tid = threadIdx.x;
  const int bid = blockIdx.x;
  const int b = bid >> 3, sblk = bid & 7;

  __shared__ float h_s[512];
  __shared__ float gates_s[256];
  __shared__ float red2[64][4];
  __shared__ float dec_s[64];
  __shared__ float wf_s[64];
  __shared__ float sm[256];
  __shared__ float tmp[256];
  __shared__ float part[256];
  __shared__ short As12[12 * 32 * 32];
  __shared__ short Bs12[12 * 64 * 32];

  float cc0 = 0.f, cc1 = 0.f;  // c[u0], c[u0+1] for tid<32, u0 = sblk*64+2*tid

  for (int tau = 0; tau <= 50; ++tau) {
    // ======== p1a: finalize h-slice [sblk*64, +64) ========
    if (tau > 0) {
      {
        const int g = tid >> 6, ul = tid & 63;
        const int u = sblk * 64 + ul;
        float v = __builtin_nontemporal_load(
            gates_x + (size_t)(b * 50 + tau - 1) * 2048 + g * 512 + u);
#pragma unroll
        for (int kp = 0; kp < 8; ++kp)
          v += cloadf(gpart + (size_t)(kp * 32 + b) * 2048 + g * 512 + u);
        gates_s[g * 64 + ul] = v;
      }
      __syncthreads();
      if (tid < 32) {
        const int l0 = tid << 1;
        const int u0 = sblk * 64 + l0;
        float gi0 = gates_s[l0], gi1 = gates_s[l0 + 1];
        float gf0 = gates_s[64 + l0], gf1 = gates_s[64 + l0 + 1];
        float gg0 = gates_s[128 + l0], gg1 = gates_s[128 + l0 + 1];
        float go0 = gates_s[192 + l0], go1 = gates_s[192 + l0 + 1];
        float si0 = 1.f / (1.f + expf(-gi0)), si1 = 1.f / (1.f + expf(-gi1));
        float sf0 = 1.f / (1.f + expf(-gf0)), sf1 = 1.f / (1.f + expf(-gf1));
        float so0 = 1.f / (1.f + expf(-go0)), so1 = 1.f / (1.f + expf(-go1));
        float cn0 = sf0 * cc0 + si0 * tanhf(gg0);
        float cn1 = sf1 * cc1 + si1 * tanhf(gg1);
        float hn0 = so0 * tanhf(cn0), hn1 = so1 * tanhf(cn1);
        cc0 = cn0; cc1 = cn1;
        float2 hp; hp.x = hn0; hp.y = hn1;
        cstore64(hbuf + (size_t)b * 512 + u0, __builtin_bit_cast(u64, hp));
        unsigned short h0hi = f2bf(hn0), h1hi = f2bf(hn1);
        unsigned short h0lo = f2bf(hn0 - bf2f(h0hi)), h1lo = f2bf(hn1 - bf2f(h1hi));
        unsigned int phi = (unsigned int)h0hi | ((unsigned int)h1hi << 16);
        unsigned int plo = (unsigned int)h0lo | ((unsigned int)h1lo << 16);
        const size_t hrow = (size_t)(b * 50 + tau - 1) * 1024;
        __builtin_nontemporal_store(phi, (unsigned int*)(H2 + hrow + u0));
        __builtin_nontemporal_store(plo, (unsigned int*)(H2 + hrow + 512 + u0));
        cstore32(xh2 + b * 2048 + 512 + u0, phi);   // h_hi pair
        cstore32(xh2 + b * 2048 + 1536 + u0, plo);  // h_lo pair
      }
    } else {
      if (tid < 32) {
        const int u0 = sblk * 64 + (tid << 1);
        cstore64(hbuf + (size_t)b * 512 + u0, 0ull);
        cstore32(xh2 + b * 2048 + 512 + u0, 0u);
        cstore32(xh2 + b * 2048 + 1536 + u0, 0u);
      }
    }
    if (tau == 50) break;  // finalize-only tail
    gbar(bar + (size_t)(4 * tau) * BARSTRIDE);

    // ======== p1b: full h from hbuf, dec_att a-slice, partial scores ========
    {
      float2 hp = bc2(cload64(hbuf + (size_t)b * 512 + (tid << 1)));
      h_s[tid << 1] = hp.x; h_s[(tid << 1) + 1] = hp.y;
    }
    __syncthreads();
    const int abase = sblk * 64;
    {
      const int al = tid >> 2, qq = tid & 3;
      const unsigned short* wr = Wdec2 + (size_t)(abase + al) * 512 + qq * 128;
      float p = 0.f;
#pragma unroll
      for (int i = 0; i < 16; ++i) {
        short8 w8 = *(const short8*)(wr + i * 8);
        const float* hh = &h_s[qq * 128 + i * 8];
#pragma unroll
        for (int e = 0; e < 8; ++e) p += bf2f((unsigned short)w8[e]) * hh[e];
      }
      red2[al][qq] = p;
    }
    __syncthreads();
    if (tid < 64) {
      dec_s[tid] = red2[tid][0] + red2[tid][1] + red2[tid][2] + red2[tid][3] + b_dec[abase + tid];
      wf_s[tid] = Wfull[abase + tid];
    }
    __syncthreads();
    if (tid < 196) {
      const unsigned short* er = encbf + (size_t)(b * 196 + tid) * 512 + abase;
      float s = 0.f;
#pragma unroll
      for (int i = 0; i < 8; ++i) {
        short8 e8 = *(const short8*)(er + i * 8);
#pragma unroll
        for (int a = 0; a < 8; ++a)
          s += wf_s[i * 8 + a] * fmaxf(bf2f((unsigned short)e8[a]) + dec_s[i * 8 + a], 0.f);
      }
      cstoref(spart + ((size_t)(b * 196 + tid)) * 8 + sblk, s);
    }
    gbar(bar + (size_t)(4 * tau + 1) * BARSTRIDE);

    // ======== p2: combine scores, softmax (replicated), awe e-slice ========
    {
      float s;
      if (tid < 196) {
        const float* sp = spart + (size_t)(b * 196 + tid) * 8;
        float2 q0 = bc2(cload64(sp)), q1 = bc2(cload64(sp + 2));
        float2 q2 = bc2(cload64(sp + 4)), q3 = bc2(cload64(sp + 6));
        s = ((q0.x + q0.y) + (q1.x + q1.y)) + ((q2.x + q2.y) + (q3.x + q3.y));
      } else s = -1e30f;
      sm[tid] = s;
      tmp[tid] = s;
      __syncthreads();
      for (int st = 128; st > 0; st >>= 1) {
        if (tid < st) tmp[tid] = fmaxf(tmp[tid], tmp[tid + st]);
        __syncthreads();
      }
      const float mx = tmp[0];
      __syncthreads();
      const float e = (tid < 196) ? expf(sm[tid] - mx) : 0.f;
      tmp[tid] = e;
      __syncthreads();
      for (int st = 128; st > 0; st >>= 1) {
        if (tid < st) tmp[tid] += tmp[tid + st];
        __syncthreads();
      }
      const float inv = 1.f / tmp[0];
      __syncthreads();
      sm[tid] = e * inv;  // alpha
      __syncthreads();
      // awe e-slice: wave qw covers p-range [qw*49, +49); feat from F2-hi (bf16)
      const int qw = tid >> 6, el = tid & 63;
      const int ebase = sblk * 64;
      float p = 0.f;
      for (int pp = qw * 49; pp < qw * 49 + 49; ++pp)
        p += sm[pp] * bf2f(F2[(size_t)(b * 196 + pp) * 1024 + ebase + el]);
      part[tid] = p;
      __syncthreads();
      if (tid < 32) {
        const int e0 = tid << 1;
        float a0 = part[e0] + part[64 + e0] + part[128 + e0] + part[192 + e0];
        float a1 = part[e0 + 1] + part[64 + e0 + 1] + part[128 + e0 + 1] + part[192 + e0 + 1];
        unsigned short a0hi = f2bf(a0), a1hi = f2bf(a1);
        unsigned short a0lo = f2bf(a0 - bf2f(a0hi)), a1lo = f2bf(a1 - bf2f(a1hi));
        cstore32(xh2 + b * 2048 + ebase + e0,
                 (unsigned int)a0hi | ((unsigned int)a1hi << 16));
        cstore32(xh2 + b * 2048 + 1024 + ebase + e0,
                 (unsigned int)a0lo | ((unsigned int)a1lo << 16));
      }
    }
    gbar(bar + (size_t)(4 * tau + 2) * BARSTRIDE);

    // ======== p3: gates GEMM, batch-staged 12 k-steps -> 24 MFMAs ========
    {
      const int lane = tid & 63;
      const int w = tid >> 6;
      const int jbase = (bid >> 3) * 64;  // j-tile (reuses b index slot)
      const int kblk = sblk;              // k-slice
      const int r2 = tid >> 2, ce = (tid & 3) << 3;
      u64 a0r[12], a1r[12];
#pragma unroll
      for (int s = 0; s < 12; ++s) {
        int ks = kblk * 12 + s;  // 96 total k-steps: 3 terms x 32
        int t_ = ks >> 5, k = (ks & 31) << 5;
        int acol = (t_ == 2) ? 1024 + k : k;
        int bcol = (t_ == 1) ? 1024 + k : k;
        if (tid < 128) {
          const unsigned short* ap = xh2 + (size_t)r2 * 2048 + acol + ce;
          a0r[s] = cload64(ap);
          a1r[s] = cload64(ap + 4);
        }
        gl_lds16(Wcat2 + (size_t)(jbase + r2) * 2048 + bcol + ce, Bs12 + s * 2048 + tid * 8);
      }
      if (tid < 128) {
#pragma unroll
        for (int s = 0; s < 12; ++s) {
          *(u64*)(As12 + s * 1024 + tid * 8) = a0r[s];
          *(u64*)(As12 + s * 1024 + tid * 8 + 4) = a1r[s];
        }
      }
      __syncthreads();
      f32x4 acc0 = (f32x4){0.f, 0.f, 0.f, 0.f}, acc1 = (f32x4){0.f, 0.f, 0.f, 0.f};
#pragma unroll
      for (int s = 0; s < 12; ++s) {
        short8 a0f = *(const short8*)(As12 + s * 1024 + (lane & 15) * 32 + (lane >> 4) * 8);
        short8 a1f = *(const short8*)(As12 + s * 1024 + (16 + (lane & 15)) * 32 + (lane >> 4) * 8);
        short8 bbf = *(const short8*)(Bs12 + s * 2048 + (w * 16 + (lane & 15)) * 32 + (lane >> 4) * 8);
        acc0 = __builtin_amdgcn_mfma_f32_16x16x32_bf16(a0f, bbf, acc0, 0, 0, 0);
        acc1 = __builtin_amdgcn_mfma_f32_16x16x32_bf16(a1f, bbf, acc1, 0, 0, 0);
      }
      const int j = jbase + w * 16 + (lane & 15);
#pragma unroll
      for (int rr = 0; rr < 4; ++rr) {
        const int brow = (lane >> 4) * 4 + rr;
        cstoref(&gpart[(size_t)(kblk * 32 + brow) * 2048 + j], acc0[rr]);
        cstoref(&gpart[(size_t)(kblk * 32 + 16 + brow) * 2048 + j], acc1[rr]);
      }
    }
    gbar(bar + (size_t)(4 * tau + 3) * BARSTRIDE);
  }
}

extern "C" void kernel_launch(void* const* d_in, const int* in_sizes, int n_in,
                              void* d_out, int out_size, void* d_ws, size_t ws_size,
                              hipStream_t stream) {
  const float* features = (const float*)d_in[0];
  const int* captions   = (const int*)d_in[1];
  const float* emb      = (const float*)d_in[2];
  const float* W_ih     = (const float*)d_in[3];
  const float* b_ih     = (const float*)d_in[4];
  const float* W_hh     = (const float*)d_in[5];
  const float* b_hh     = (const float*)d_in[6];
  const float* W_enc    = (const float*)d_in[7];
  const float* b_enc    = (const float*)d_in[8];
  const float* W_dec    = (const float*)d_in[9];
  const float* b_dec    = (const float*)d_in[10];
  const float* W_full   = (const float*)d_in[11];
  // d_in[12] = b_full: constant shift before softmax -> no-op, skipped
  const float* W_out    = (const float*)d_in[13];
  const float* b_out    = (const float*)d_in[14];
  float* out = (float*)d_out;
  (void)in_sizes; (void)n_in; (void)out_size; (void)ws_size;

  char* ws = (char*)d_ws;
  size_t off = 0;
  auto alloc = [&](size_t bytes) -> void* {
    void* p = ws + off;
    off = (off + bytes + 255) & ~(size_t)255;
    return p;
  };
  float* encatt         = (float*)alloc(6272ull * 512 * 4);
  unsigned short* encbf = (unsigned short*)alloc(6272ull * 512 * 2);
  unsigned short* F2    = (unsigned short*)alloc(6272ull * 1024 * 2);
  unsigned short* We2   = (unsigned short*)alloc(512ull * 1024 * 2);
  unsigned short* X2    = (unsigned short*)alloc(1600ull * 1024 * 2);
  unsigned short* WihX2 = (unsigned short*)alloc(2048ull * 1024 * 2);
  unsigned short* Wout2 = (unsigned short*)alloc(32000ull * 1024 * 2);
  unsigned short* H2    = (unsigned short*)alloc(1600ull * 1024 * 2);
  float* gates_x        = (float*)alloc(1600ull * 2048 * 4);
  unsigned short* Wcat2 = (unsigned short*)alloc(2048ull * 2048 * 2);
  unsigned short* Wdec2 = (unsigned short*)alloc(512ull * 512 * 2);
  unsigned short* xh2   = (unsigned short*)alloc(32ull * 2048 * 2);
  float* spart          = (float*)alloc(32ull * 196 * 8 * 4);
  float* gpart          = (float*)alloc(8ull * 32 * 2048 * 4);
  float* hbuf           = (float*)alloc(32ull * 512 * 4);
  unsigned int* bar     = (unsigned int*)alloc((size_t)NBAR * BARSTRIDE * 4);

  // ---- prep (hoisted, data-parallel)
  k_zero<<<(NBAR * BARSTRIDE + 255) / 256, 256, 0, stream>>>(bar, NBAR * BARSTRIDE);
  k_split<<<2048, 256, 0, stream>>>(features, F2, 6272, 512);
  k_split<<<512, 256, 0, stream>>>(W_enc, We2, 512, 512);
  k_split<<<2048, 256, 0, stream>>>(W_ih, WihX2, 2048, 1024);   // x_t half of W_ih
  k_split<<<2048, 256, 0, stream>>>(W_out, Wout2, 32000, 512);
  k_bf16c<<<512, 256, 0, stream>>>(W_dec, Wdec2, 512 * 512);
  k_wcat2<<<2048, 256, 0, stream>>>(W_ih, W_hh, Wcat2);
  k_xgather<<<2048, 256, 0, stream>>>(captions, emb, X2);

  // ---- hoisted GEMMs
  // enc_att = features @ W_enc^T + b_enc   [6272, 512]
  k_gemm<<<dim3(4, 49), 256, 0, stream>>>(F2, We2, encatt, b_enc, nullptr, 6272, 512);
  // gates_x = emb(captions) @ W_ih[:, :512]^T + b_ih + b_hh   [1600, 2048]
  k_gemm<<<dim3(16, 13), 256, 0, stream>>>(X2, WihX2, gates_x, b_ih, b_hh, 1600, 2048);
  // encatt -> bf16 (halves the L2-resident attention read set)
  k_bf16c<<<2048, 256, 0, stream>>>(encatt, encbf, 6272 * 512);

  // ---- sequential scan: one persistent kernel, cheap coherent barriers
  k_scan<<<256, 256, 0, stream>>>(gates_x, H2, xh2, Wdec2, b_dec, encbf, W_full,
                                  F2, Wcat2, gpart, spart, hbuf, bar);

  // ---- final: out[b,t,:] = h_{t+1}[b] @ W_out^T + b_out  (rows already b*50+t)
  k_gemm<<<dim3(250, 13), 256, 0, stream>>>(H2, Wout2, out, b_out, nullptr, 1600, 32000);
}

// Round 6
// 2269.369 us; speedup vs baseline: 1.2342x; 1.2342x over previous
//
#include <hip/hip_runtime.h>
#include <hip/hip_bf16.h>

// DecoderRNN: B=32,P=196,E=H=A=512,V=32000,T=50
// v7: LAUNCH-based scan again (persistent+grid-barrier loses: 256-block atomic
//     barrier ~8-13us each, rounds 2-5).  vs round-0 baseline:
//     - 2 launches/step (p1+p2 fused: full dec_att + full scores per block,
//       replication instead of spart exchange; scores read bf16 enc_att (v6-validated))
//     - k_pB batch-stages 12 k-steps (72KB LDS) -> 24 back-to-back MFMAs
//     - k_gemm: bijective XCD-chunked swizzle (M-fastest) + direct bf16 output
//     - cbuf replicated per (eblk,b): no cross-block c race

typedef __attribute__((ext_vector_type(8))) short short8;
typedef __attribute__((ext_vector_type(4))) float f32x4;

__device__ __forceinline__ unsigned short f2bf(float x) {
  __hip_bfloat16 h = __float2bfloat16(x);
  return __builtin_bit_cast(unsigned short, h);
}
__device__ __forceinline__ float bf2f(unsigned short u) {
  unsigned int v = ((unsigned int)u) << 16;
  return __builtin_bit_cast(float, v);
}
__device__ __forceinline__ void gl_lds16(const void* g, void* l) {
  __builtin_amdgcn_global_load_lds(
      (const __attribute__((address_space(1))) unsigned int*)g,
      (__attribute__((address_space(3))) unsigned int*)l, 16, 0, 0);
}

// ---- prep: f32 [rows,512] -> bf16 split [rows,1024] ([0,512)=hi, [512,1024)=lo)
__global__ void k_split(const float* __restrict__ src, unsigned short* __restrict__ dst,
                        int rows, int src_ld) {
  int n = rows * 512;
  for (int i = blockIdx.x * blockDim.x + threadIdx.x; i < n; i += gridDim.x * blockDim.x) {
    int r = i >> 9, c = i & 511;
    float x = src[(size_t)r * src_ld + c];
    unsigned short hi = f2bf(x);
    unsigned short lo = f2bf(x - bf2f(hi));
    dst[(size_t)r * 1024 + c] = hi;
    dst[(size_t)r * 1024 + 512 + c] = lo;
  }
}

// ---- prep: plain f32 -> bf16
__global__ void k_bf16c(const float* __restrict__ src, unsigned short* __restrict__ dst, int n) {
  for (int i = blockIdx.x * blockDim.x + threadIdx.x; i < n; i += gridDim.x * blockDim.x)
    dst[i] = f2bf(src[i]);
}

// ---- prep: Wcat2 [2048 j][2048]: cols [0,512)=hi(W_ih[j,512+c]) [512,1024)=hi(W_hh[j,c]),
//      [1024,2048) = same but lo.  Matches xh2 layout [awe_hi|h_hi|awe_lo|h_lo].
__global__ void k_wcat2(const float* __restrict__ Wih, const float* __restrict__ Whh,
                        unsigned short* __restrict__ dst) {
  int n = 2048 * 1024;
  for (int i = blockIdx.x * blockDim.x + threadIdx.x; i < n; i += gridDim.x * blockDim.x) {
    int j = i >> 10, c = i & 1023;
    float x = (c < 512) ? Wih[(size_t)j * 1024 + 512 + c] : Whh[(size_t)j * 512 + (c - 512)];
    unsigned short hi = f2bf(x);
    unsigned short lo = f2bf(x - bf2f(hi));
    dst[(size_t)j * 2048 + c] = hi;
    dst[(size_t)j * 2048 + 1024 + c] = lo;
  }
}

// ---- prep: X2 [1600,1024] split-bf16 of emb[captions]; row m = b*50+t
__global__ void k_xgather(const int* __restrict__ captions, const float* __restrict__ emb,
                          unsigned short* __restrict__ X2) {
  int n = 1600 * 512;
  for (int i = blockIdx.x * blockDim.x + threadIdx.x; i < n; i += gridDim.x * blockDim.x) {
    int m = i >> 9, c = i & 511;
    int tok = captions[m];
    float x = emb[(size_t)tok * 512 + c];
    unsigned short hi = f2bf(x);
    unsigned short lo = f2bf(x - bf2f(hi));
    X2[(size_t)m * 1024 + c] = hi;
    X2[(size_t)m * 1024 + 512 + c] = lo;
  }
}

// ---- split-bf16 GEMM: C[m,n] = sum_k A[m,:]·B[n,:] (3-term hi/lo) + bias1[n] + bias2[n]
// A2 [M,1024], B2 [N,1024]. 128x128 tile, m97 pattern.  Output f32 (C) or bf16 (C16).
// Bijective XCD-chunked swizzle, M-fastest decode: same-N-panel tiles co-reside on one XCD.
__global__ void k_gemm(const unsigned short* __restrict__ A2, const unsigned short* __restrict__ B2,
                       float* __restrict__ C, unsigned short* __restrict__ C16,
                       const float* __restrict__ bias1, const float* __restrict__ bias2,
                       int M, int N) {
  __shared__ short As[128 * 32];
  __shared__ short Bs[128 * 32];
  const int tid = threadIdx.x;
  const int lane = tid & 63;
  const int w = tid >> 6, wm = w >> 1, wn = w & 1;

  const int nbx = gridDim.x, nby = gridDim.y;
  const int nwg = nbx * nby;
  const int bidl = blockIdx.y * nbx + blockIdx.x;
  int flat = bidl;
  if (nwg >= 16) {  // bijective chunked XCD swizzle (m204 formula)
    const int q = nwg >> 3, rrem = nwg & 7;
    const int xcd = bidl & 7, idx = bidl >> 3;
    flat = (xcd < rrem) ? xcd * (q + 1) + idx : rrem * (q + 1) + (xcd - rrem) * q + idx;
  }
  const int mb = flat % nby, nb = flat / nby;  // M fastest: same-N tiles contiguous
  const int m0 = mb * 128, n0 = nb * 128;

  f32x4 acc[4][4];
#pragma unroll
  for (int i = 0; i < 4; ++i)
#pragma unroll
    for (int j = 0; j < 4; ++j) acc[i][j] = (f32x4){0.f, 0.f, 0.f, 0.f};

  const int r0 = tid >> 2;
  const int ce = (tid & 3) << 3;
  int am0 = m0 + r0;      if (am0 >= M) am0 = 0;
  int am1 = m0 + 64 + r0; if (am1 >= M) am1 = 0;
  const int bn0 = n0 + r0, bn1 = n0 + 64 + r0;

  for (int ks = 0; ks < 48; ++ks) {
    int t_ = ks >> 4, k = (ks & 15) << 5;
    int acol = (t_ == 2) ? 512 + k : k;
    int bcol = (t_ == 1) ? 512 + k : k;
    __syncthreads();
    gl_lds16(A2 + (size_t)am0 * 1024 + acol + ce, As + tid * 8);
    gl_lds16(A2 + (size_t)am1 * 1024 + acol + ce, As + 2048 + tid * 8);
    gl_lds16(B2 + (size_t)bn0 * 1024 + bcol + ce, Bs + tid * 8);
    gl_lds16(B2 + (size_t)bn1 * 1024 + bcol + ce, Bs + 2048 + tid * 8);
    __syncthreads();
    short8 af[4], bf[4];
#pragma unroll
    for (int mi = 0; mi < 4; ++mi) {
      int row = wm * 64 + mi * 16 + (lane & 15);
      af[mi] = *(const short8*)(As + row * 32 + (lane >> 4) * 8);
    }
#pragma unroll
    for (int ni = 0; ni < 4; ++ni) {
      int row = wn * 64 + ni * 16 + (lane & 15);
      bf[ni] = *(const short8*)(Bs + row * 32 + (lane >> 4) * 8);
    }
#pragma unroll
    for (int mi = 0; mi < 4; ++mi)
#pragma unroll
      for (int ni = 0; ni < 4; ++ni)
        acc[mi][ni] = __builtin_amdgcn_mfma_f32_16x16x32_bf16(af[mi], bf[ni], acc[mi][ni], 0, 0, 0);
  }

  const int mbb = m0 + wm * 64, nbb = n0 + wn * 64;
#pragma unroll
  for (int ni = 0; ni < 4; ++ni) {
    int n = nbb + ni * 16 + (lane & 15);
    float bv = 0.f;
    if (bias1) bv += bias1[n];
    if (bias2) bv += bias2[n];
#pragma unroll
    for (int mi = 0; mi < 4; ++mi)
#pragma unroll
      for (int r = 0; r < 4; ++r) {
        int m = mbb + mi * 16 + (lane >> 4) * 4 + r;
        if (m < M) {
          float v = acc[mi][ni][r] + bv;
          if (C16) C16[(size_t)m * N + n] = f2bf(v);
          else C[(size_t)m * N + n] = v;
        }
      }
  }
}

// ---- phase A (per step): finalize LSTM (replicated; private cbuf copy) + FULL dec_att +
//      FULL scores (bf16 enc_att) + softmax + awe e-slice -> xh2.  grid 256 = (b, eblk).
__global__ void k_pA(int tau, const float* __restrict__ gpart, const float* __restrict__ gates_x,
                     float* __restrict__ cbuf, unsigned short* __restrict__ H2,
                     unsigned short* __restrict__ xh2, const unsigned short* __restrict__ Wdec2,
                     const float* __restrict__ b_dec, const unsigned short* __restrict__ encbf,
                     const float* __restrict__ Wfull, const unsigned short* __restrict__ F2) {
  const int b = blockIdx.x >> 3, eblk = blockIdx.x & 7;
  const int tid = threadIdx.x;
  __shared__ float h_s[512];
  __shared__ float dec_s[512];
  __shared__ float wf_s[512];
  __shared__ float sm[256], tmp[256], part[256];

  float* cb = cbuf + ((size_t)eblk * 32 + b) * 512;  // private replica -> no cross-block race
  if (tau > 0) {
    const float* gx = gates_x + (size_t)(b * 50 + (tau - 1)) * 2048;
    for (int u = tid; u < 512; u += 256) {
      float gi = gx[u], gf = gx[512 + u], gg = gx[1024 + u], go = gx[1536 + u];
#pragma unroll
      for (int kp = 0; kp < 8; ++kp) {
        const float* gp = gpart + (size_t)(kp * 32 + b) * 2048;
        gi += gp[u]; gf += gp[512 + u]; gg += gp[1024 + u]; go += gp[1536 + u];
      }
      float c_old = cb[u];
      float si = 1.f / (1.f + expf(-gi));
      float sf = 1.f / (1.f + expf(-gf));
      float so = 1.f / (1.f + expf(-go));
      float cn = sf * c_old + si * tanhf(gg);
      float hn = so * tanhf(cn);
      cb[u] = cn;
      h_s[u] = hn;
      if (eblk == 0) {
        unsigned short hi = f2bf(hn), lo = f2bf(hn - bf2f(hi));
        size_t hrow = (size_t)(b * 50 + (tau - 1)) * 1024;
        H2[hrow + u] = hi; H2[hrow + 512 + u] = lo;
        xh2[b * 2048 + 512 + u] = hi;   // h_hi
        xh2[b * 2048 + 1536 + u] = lo;  // h_lo
      }
    }
  } else {
    for (int u = tid; u < 512; u += 256) {
      h_s[u] = 0.f;
      cb[u] = 0.f;  // re-init every call (graph replay safe)
      if (eblk == 0) {
        xh2[b * 2048 + 512 + u] = 0;
        xh2[b * 2048 + 1536 + u] = 0;
      }
    }
  }
  if (tau >= 50) return;  // finalize-only launch
  __syncthreads();

  // ---- full dec_att: dec_s[a] = sum_k bf16(W_dec[a,k])*h[k] + b_dec[a]; + wf load
#pragma unroll
  for (int half = 0; half < 2; ++half) {
    const int a = tid + half * 256;
    const short8* wr = (const short8*)(Wdec2 + (size_t)a * 512);
    float p0 = 0.f, p1 = 0.f, p2 = 0.f, p3 = 0.f;
#pragma unroll 4
    for (int i = 0; i < 64; ++i) {
      short8 w8 = wr[i];
      const float* hh = &h_s[i * 8];
      p0 += bf2f((unsigned short)w8[0]) * hh[0];
      p1 += bf2f((unsigned short)w8[1]) * hh[1];
      p2 += bf2f((unsigned short)w8[2]) * hh[2];
      p3 += bf2f((unsigned short)w8[3]) * hh[3];
      p0 += bf2f((unsigned short)w8[4]) * hh[4];
      p1 += bf2f((unsigned short)w8[5]) * hh[5];
      p2 += bf2f((unsigned short)w8[6]) * hh[6];
      p3 += bf2f((unsigned short)w8[7]) * hh[7];
    }
    dec_s[a] = (p0 + p1) + (p2 + p3) + b_dec[a];
    wf_s[a] = Wfull[a];
  }
  __syncthreads();

  // ---- full scores: s[p] = sum_a wf[a]*relu(encbf[b,p,a]+dec[a])
  float s = -1e30f;
  if (tid < 196) {
    const unsigned short* er = encbf + (size_t)(b * 196 + tid) * 512;
    float a0 = 0.f, a1 = 0.f, a2 = 0.f, a3 = 0.f;
#pragma unroll 4
    for (int i = 0; i < 64; ++i) {
      short8 e8 = *(const short8*)(er + i * 8);
      a0 += wf_s[i * 8 + 0] * fmaxf(bf2f((unsigned short)e8[0]) + dec_s[i * 8 + 0], 0.f);
      a1 += wf_s[i * 8 + 1] * fmaxf(bf2f((unsigned short)e8[1]) + dec_s[i * 8 + 1], 0.f);
      a2 += wf_s[i * 8 + 2] * fmaxf(bf2f((unsigned short)e8[2]) + dec_s[i * 8 + 2], 0.f);
      a3 += wf_s[i * 8 + 3] * fmaxf(bf2f((unsigned short)e8[3]) + dec_s[i * 8 + 3], 0.f);
      a0 += wf_s[i * 8 + 4] * fmaxf(bf2f((unsigned short)e8[4]) + dec_s[i * 8 + 4], 0.f);
      a1 += wf_s[i * 8 + 5] * fmaxf(bf2f((unsigned short)e8[5]) + dec_s[i * 8 + 5], 0.f);
      a2 += wf_s[i * 8 + 6] * fmaxf(bf2f((unsigned short)e8[6]) + dec_s[i * 8 + 6], 0.f);
      a3 += wf_s[i * 8 + 7] * fmaxf(bf2f((unsigned short)e8[7]) + dec_s[i * 8 + 7], 0.f);
    }
    s = (a0 + a1) + (a2 + a3);
  }
  sm[tid] = s;
  tmp[tid] = s;
  __syncthreads();
  for (int st = 128; st > 0; st >>= 1) {
    if (tid < st) tmp[tid] = fmaxf(tmp[tid], tmp[tid + st]);
    __syncthreads();
  }
  const float mx = tmp[0];
  __syncthreads();
  const float e = (tid < 196) ? expf(sm[tid] - mx) : 0.f;
  tmp[tid] = e;
  __syncthreads();
  for (int st = 128; st > 0; st >>= 1) {
    if (tid < st) tmp[tid] += tmp[tid + st];
    __syncthreads();
  }
  const float inv = 1.f / tmp[0];
  __syncthreads();
  sm[tid] = e * inv;  // alpha
  __syncthreads();

  // ---- awe e-slice [eblk*64,+64): wave qw covers p-range [qw*49,+49); feat = F2-hi (bf16)
  const int qw = tid >> 6, el = tid & 63;
  const int ebase = eblk * 64;
  float p = 0.f;
  for (int pp = qw * 49; pp < qw * 49 + 49; ++pp)
    p += sm[pp] * bf2f(F2[(size_t)(b * 196 + pp) * 1024 + ebase + el]);
  part[tid] = p;
  __syncthreads();
  if (tid < 64) {
    float aw = part[tid] + part[64 + tid] + part[128 + tid] + part[192 + tid];
    unsigned short hi = f2bf(aw), lo = f2bf(aw - bf2f(hi));
    xh2[b * 2048 + ebase + tid] = hi;         // awe_hi
    xh2[b * 2048 + 1024 + ebase + tid] = lo;  // awe_lo
  }
}

// ---- phase B: gates partial GEMM, batch-staged: 24 gl_lds16 -> 1 sync -> 24 MFMAs.
//      grid 256 = (nblk 32, kblk 8); gpart[kblk][b][j] partial over k-slice.
__global__ void k_pB(const unsigned short* __restrict__ xh2, const unsigned short* __restrict__ Wcat2,
                     float* __restrict__ gpart) {
  __shared__ short As12[12 * 32 * 32];
  __shared__ short Bs12[12 * 64 * 32];
  const int tid = threadIdx.x;
  const int lane = tid & 63;
  const int w = tid >> 6;
  const int nblk = blockIdx.x >> 3, kblk = blockIdx.x & 7;
  const int jbase = nblk * 64;
  const int r = tid >> 2, ce = (tid & 3) << 3;
#pragma unroll
  for (int s = 0; s < 12; ++s) {
    int ks = kblk * 12 + s;  // 96 total k-steps: 3 terms x 32
    int t_ = ks >> 5, k = (ks & 31) << 5;
    int acol = (t_ == 2) ? 1024 + k : k;
    int bcol = (t_ == 1) ? 1024 + k : k;
    if (tid < 128) gl_lds16(xh2 + (size_t)r * 2048 + acol + ce, As12 + s * 1024 + tid * 8);
    gl_lds16(Wcat2 + (size_t)(jbase + r) * 2048 + bcol + ce, Bs12 + s * 2048 + tid * 8);
  }
  __syncthreads();
  f32x4 acc0 = (f32x4){0.f, 0.f, 0.f, 0.f}, acc1 = (f32x4){0.f, 0.f, 0.f, 0.f};
#pragma unroll
  for (int s = 0; s < 12; ++s) {
    short8 a0f = *(const short8*)(As12 + s * 1024 + (lane & 15) * 32 + (lane >> 4) * 8);
    short8 a1f = *(const short8*)(As12 + s * 1024 + (16 + (lane & 15)) * 32 + (lane >> 4) * 8);
    short8 bbf = *(const short8*)(Bs12 + s * 2048 + (w * 16 + (lane & 15)) * 32 + (lane >> 4) * 8);
    acc0 = __builtin_amdgcn_mfma_f32_16x16x32_bf16(a0f, bbf, acc0, 0, 0, 0);
    acc1 = __builtin_amdgcn_mfma_f32_16x16x32_bf16(a1f, bbf, acc1, 0, 0, 0);
  }
  const int j = jbase + w * 16 + (lane & 15);
#pragma unroll
  for (int rr = 0; rr < 4; ++rr) {
    const int brow = (lane >> 4) * 4 + rr;
    gpart[(size_t)(kblk * 32 + brow) * 2048 + j] = acc0[rr];
    gpart[(size_t)(kblk * 32 + 16 + brow) * 2048 + j] = acc1[rr];
  }
}

extern "C" void kernel_launch(void* const* d_in, const int* in_sizes, int n_in,
                              void* d_out, int out_size, void* d_ws, size_t ws_size,
                              hipStream_t stream) {
  const float* features = (const float*)d_in[0];
  const int* captions   = (const int*)d_in[1];
  const float* emb      = (const float*)d_in[2];
  const float* W_ih     = (const float*)d_in[3];
  const float* b_ih     = (const float*)d_in[4];
  const float* W_hh     = (const float*)d_in[5];
  const float* b_hh     = (const float*)d_in[6];
  const float* W_enc    = (const float*)d_in[7];
  const float* b_enc    = (const float*)d_in[8];
  const float* W_dec    = (const float*)d_in[9];
  const float* b_dec    = (const float*)d_in[10];
  const float* W_full   = (const float*)d_in[11];
  // d_in[12] = b_full: constant shift before softmax -> no-op, skipped
  const float* W_out    = (const float*)d_in[13];
  const float* b_out    = (const float*)d_in[14];
  float* out = (float*)d_out;
  (void)in_sizes; (void)n_in; (void)out_size; (void)ws_size;

  char* ws = (char*)d_ws;
  size_t off = 0;
  auto alloc = [&](size_t bytes) -> void* {
    void* p = ws + off;
    off = (off + bytes + 255) & ~(size_t)255;
    return p;
  };
  unsigned short* encbf = (unsigned short*)alloc(6272ull * 512 * 2);
  unsigned short* F2    = (unsigned short*)alloc(6272ull * 1024 * 2);
  unsigned short* We2   = (unsigned short*)alloc(512ull * 1024 * 2);
  unsigned short* X2    = (unsigned short*)alloc(1600ull * 1024 * 2);
  unsigned short* WihX2 = (unsigned short*)alloc(2048ull * 1024 * 2);
  unsigned short* Wout2 = (unsigned short*)alloc(32000ull * 1024 * 2);
  unsigned short* H2    = (unsigned short*)alloc(1600ull * 1024 * 2);
  float* gates_x        = (float*)alloc(1600ull * 2048 * 4);
  unsigned short* Wcat2 = (unsigned short*)alloc(2048ull * 2048 * 2);
  unsigned short* Wdec2 = (unsigned short*)alloc(512ull * 512 * 2);
  unsigned short* xh2   = (unsigned short*)alloc(32ull * 2048 * 2);
  float* cbuf           = (float*)alloc(8ull * 32 * 512 * 4);
  float* gpart          = (float*)alloc(8ull * 32 * 2048 * 4);

  // ---- prep (hoisted, data-parallel)
  k_split<<<2048, 256, 0, stream>>>(features, F2, 6272, 512);
  k_split<<<512, 256, 0, stream>>>(W_enc, We2, 512, 512);
  k_split<<<2048, 256, 0, stream>>>(W_ih, WihX2, 2048, 1024);   // x_t half of W_ih
  k_split<<<2048, 256, 0, stream>>>(W_out, Wout2, 32000, 512);
  k_bf16c<<<512, 256, 0, stream>>>(W_dec, Wdec2, 512 * 512);
  k_wcat2<<<2048, 256, 0, stream>>>(W_ih, W_hh, Wcat2);
  k_xgather<<<2048, 256, 0, stream>>>(captions, emb, X2);

  // ---- hoisted GEMMs
  // enc_att = features @ W_enc^T + b_enc  -> bf16 directly   [6272, 512]
  k_gemm<<<dim3(4, 49), 256, 0, stream>>>(F2, We2, nullptr, encbf, b_enc, nullptr, 6272, 512);
  // gates_x = emb(captions) @ W_ih[:, :512]^T + b_ih + b_hh   [1600, 2048]
  k_gemm<<<dim3(16, 13), 256, 0, stream>>>(X2, WihX2, gates_x, nullptr, b_ih, b_hh, 1600, 2048);

  // ---- sequential scan: 2 launches per step
  for (int tau = 0; tau <= 50; ++tau) {
    k_pA<<<256, 256, 0, stream>>>(tau, gpart, gates_x, cbuf, H2, xh2, Wdec2, b_dec,
                                  encbf, W_full, F2);
    if (tau < 50)
      k_pB<<<256, 256, 0, stream>>>(xh2, Wcat2, gpart);
  }

  // ---- final: out[b,t,:] = h_{t+1}[b] @ W_out^T + b_out  (rows already b*50+t)
  k_gemm<<<dim3(250, 13), 256, 0, stream>>>(H2, Wout2, out, nullptr, b_out, nullptr, 1600, 32000);
}